// Round 1
// baseline (2863.286 us; speedup 1.0000x reference)
//
#include <hip/hip_runtime.h>

#define N_NODES 50000
#define N_EDGES 1600000
#define DIM 128
#define LN_EPS 1e-10f

// ---------------------------------------------------------------------------
// Kernel 1: SpMM scatter-add.  32 lanes per edge, float4 gather of the source
// row, 4 scalar atomicAdds into the destination row.  aggr must be zeroed.
// ---------------------------------------------------------------------------
__global__ __launch_bounds__(256) void spmm_atomic(
    const float* __restrict__ feat, const int* __restrict__ rows,
    const int* __restrict__ cols, const float* __restrict__ vals,
    float* __restrict__ aggr)
{
    int t = blockIdx.x * 256 + threadIdx.x;
    int e = t >> 5;          // edge index (32 lanes per edge)
    int l = t & 31;          // lane within edge group: handles feats [4l,4l+4)
    if (e >= N_EDGES) return;
    int r = rows[e];
    int c = cols[e];
    float v = vals[e];
    float4 g = ((const float4*)(feat + (size_t)c * DIM))[l];
    float* dst = aggr + (size_t)r * DIM + l * 4;
    atomicAdd(dst + 0, v * g.x);
    atomicAdd(dst + 1, v * g.y);
    atomicAdd(dst + 2, v * g.z);
    atomicAdd(dst + 3, v * g.w);
}

// ---------------------------------------------------------------------------
// Kernel 2: fused  out = LN(ReLU(aggr @ W^T + b)) * scale + offset.
// One wave (64 lanes) per node; lane o computes outputs o and o+64.
// W staged in LDS transposed with stride 129 -> conflict-free b32 reads.
// Grid-stride over nodes amortizes the 64 KB W staging per block.
// ---------------------------------------------------------------------------
__global__ __launch_bounds__(256) void gemm_relu_ln(
    const float* __restrict__ aggr, const float* __restrict__ W,
    const float* __restrict__ bias, const float* __restrict__ scale,
    const float* __restrict__ offset, float* __restrict__ out)
{
    __shared__ float sWt[DIM * 129];  // sWt[i*129 + o] = W[o][i]

    // Cooperative coalesced load + transposed store (bank-conflict-free:
    // within a wave, i is lane-consecutive, o is uniform -> bank = (i+o)%32).
    for (int idx = threadIdx.x; idx < DIM * DIM; idx += 256) {
        int o = idx >> 7;
        int i = idx & 127;
        sWt[i * 129 + o] = W[idx];
    }
    __syncthreads();

    const int lane = threadIdx.x & 63;
    const int wid  = threadIdx.x >> 6;

    const float b0 = bias[lane],    b1 = bias[lane + 64];
    const float s0 = scale[lane],   s1 = scale[lane + 64];
    const float f0 = offset[lane],  f1 = offset[lane + 64];

    for (int n = blockIdx.x * 4 + wid; n < N_NODES; n += gridDim.x * 4) {
        // Force wave-uniform so the aggr row loads can be scalarized.
        int nu = __builtin_amdgcn_readfirstlane(n);
        const float* arow = aggr + (size_t)nu * DIM;

        float acc0 = b0, acc1 = b1;
        #pragma unroll 8
        for (int i = 0; i < DIM; ++i) {
            float a = arow[i];                       // wave-uniform broadcast
            acc0 = fmaf(a, sWt[i * 129 + lane], acc0);
            acc1 = fmaf(a, sWt[i * 129 + lane + 64], acc1);
        }

        float a0 = fmaxf(acc0, 0.0f);
        float a1 = fmaxf(acc1, 0.0f);

        // mean over 128 features (two values per lane, 64-lane butterfly)
        float s = a0 + a1;
        #pragma unroll
        for (int off = 32; off >= 1; off >>= 1) s += __shfl_xor(s, off, 64);
        float mean = s * (1.0f / 128.0f);

        float d0 = a0 - mean, d1 = a1 - mean;
        float q = d0 * d0 + d1 * d1;
        #pragma unroll
        for (int off = 32; off >= 1; off >>= 1) q += __shfl_xor(q, off, 64);
        float rstd = rsqrtf(q * (1.0f / 128.0f) + LN_EPS);

        out[(size_t)n * DIM + lane]      = d0 * s0 * rstd + f0;
        out[(size_t)n * DIM + lane + 64] = d1 * s1 * rstd + f1;
    }
}

extern "C" void kernel_launch(void* const* d_in, const int* in_sizes, int n_in,
                              void* d_out, int out_size, void* d_ws, size_t ws_size,
                              hipStream_t stream) {
    const float* feat_in = (const float*)d_in[0];
    const int*   rows    = (const int*)d_in[1];
    const int*   cols    = (const int*)d_in[2];
    const float* vals    = (const float*)d_in[3];
    const float* W       = (const float*)d_in[4];
    const float* bias    = (const float*)d_in[5];
    const float* scale   = (const float*)d_in[6];
    const float* offset  = (const float*)d_in[7];
    float* out  = (float*)d_out;
    float* aggr = (float*)d_ws;          // 50000*128*4 = 25.6 MB scratch

    // ws is re-poisoned to 0xAA before every timed call -> must zero it here.
    hipMemsetAsync(aggr, 0, (size_t)N_NODES * DIM * sizeof(float), stream);

    // SpMM: 1.6M edges * 32 lanes = 51.2M threads.
    int spmm_blocks = (N_EDGES * 32) / 256;   // = 200000, exact
    spmm_atomic<<<spmm_blocks, 256, 0, stream>>>(feat_in, rows, cols, vals, aggr);

    // Fused linear + ReLU + layernorm.
    gemm_relu_ln<<<1024, 256, 0, stream>>>(aggr, W, bias, scale, offset, out);
}

// Round 2
// 492.386 us; speedup vs baseline: 5.8151x; 5.8151x over previous
//
#include <hip/hip_runtime.h>

#define N_NODES 50000
#define N_EDGES 1600000
#define DIM 128
#define LN_EPS 1e-10f
#define SCAN_B 256
#define N_SCAN_BLOCKS ((N_NODES + SCAN_B - 1) / SCAN_B)   // 196

// ---------------------------------------------------------------------------
// CSR build: histogram -> exclusive scan -> scatter (col,val) pairs.
// Replaces 204.8M fp32 atomics (3.2 GB HBM write-through) with 1.6M int
// atomics + 12.8 MB of scattered 8B writes.
// ---------------------------------------------------------------------------
__global__ __launch_bounds__(256) void hist_kernel(
    const int* __restrict__ rows, int* __restrict__ counts)
{
    int e = blockIdx.x * 256 + threadIdx.x;
    if (e < N_EDGES) atomicAdd(&counts[rows[e]], 1);
}

__global__ __launch_bounds__(256) void scan_blocksum(
    const int* __restrict__ counts, int* __restrict__ blocksums)
{
    __shared__ int s[256];
    int i = blockIdx.x * 256 + threadIdx.x;
    s[threadIdx.x] = (i < N_NODES) ? counts[i] : 0;
    __syncthreads();
    for (int off = 128; off > 0; off >>= 1) {
        if (threadIdx.x < off) s[threadIdx.x] += s[threadIdx.x + off];
        __syncthreads();
    }
    if (threadIdx.x == 0) blocksums[blockIdx.x] = s[0];
}

__global__ __launch_bounds__(256) void scan_blockpref(
    const int* __restrict__ blocksums, int* __restrict__ blockpref)
{
    __shared__ int s[256];
    int t = threadIdx.x;
    s[t] = (t < N_SCAN_BLOCKS) ? blocksums[t] : 0;
    __syncthreads();
    for (int off = 1; off < 256; off <<= 1) {
        int v = s[t];
        int add = (t >= off) ? s[t - off] : 0;
        __syncthreads();
        s[t] = v + add;
        __syncthreads();
    }
    if (t < N_SCAN_BLOCKS) blockpref[t] = (t == 0) ? 0 : s[t - 1];
}

__global__ __launch_bounds__(256) void scan_final(
    const int* __restrict__ counts, const int* __restrict__ blockpref,
    int* __restrict__ offsets, int* __restrict__ cursor)
{
    __shared__ int s[256];
    int t = threadIdx.x;
    int i = blockIdx.x * 256 + t;
    int v = (i < N_NODES) ? counts[i] : 0;
    s[t] = v;
    __syncthreads();
    for (int off = 1; off < 256; off <<= 1) {
        int cur = s[t];
        int add = (t >= off) ? s[t - off] : 0;
        __syncthreads();
        s[t] = cur + add;
        __syncthreads();
    }
    int excl = s[t] - v + blockpref[blockIdx.x];
    if (i < N_NODES) { offsets[i] = excl; cursor[i] = excl; }
    if (i == N_NODES - 1) offsets[N_NODES] = excl + v;
}

__global__ __launch_bounds__(256) void scatter_kernel(
    const int* __restrict__ rows, const int* __restrict__ cols,
    const float* __restrict__ vals, int* __restrict__ cursor,
    int2* __restrict__ perm)
{
    int e = blockIdx.x * 256 + threadIdx.x;
    if (e >= N_EDGES) return;
    int pos = atomicAdd(&cursor[rows[e]], 1);
    perm[pos] = make_int2(cols[e], __float_as_int(vals[e]));
}

// ---------------------------------------------------------------------------
// Aggregate: one wave (64 lanes) per destination row. Uniform scalar loop
// over the row's CSR segment; float2 coalesced gather of source rows;
// single float2 store per lane at the end. No atomics.
// ---------------------------------------------------------------------------
__global__ __launch_bounds__(256) void aggregate_kernel(
    const int2* __restrict__ perm, const int* __restrict__ offsets,
    const float* __restrict__ feat, float* __restrict__ aggr)
{
    int w = (blockIdx.x * 256 + threadIdx.x) >> 6;   // one row per wave
    int lane = threadIdx.x & 63;
    if (w >= N_NODES) return;
    int beg = offsets[w];
    int end = offsets[w + 1];

    float ax = 0.0f, ay = 0.0f;
    int e = beg;
    for (; e + 1 < end; e += 2) {
        int2 p0 = perm[e];
        int2 p1 = perm[e + 1];
        float2 g0 = ((const float2*)(feat + (size_t)p0.x * DIM))[lane];
        float2 g1 = ((const float2*)(feat + (size_t)p1.x * DIM))[lane];
        float v0 = __int_as_float(p0.y);
        float v1 = __int_as_float(p1.y);
        ax = fmaf(v0, g0.x, ax);  ay = fmaf(v0, g0.y, ay);
        ax = fmaf(v1, g1.x, ax);  ay = fmaf(v1, g1.y, ay);
    }
    if (e < end) {
        int2 p = perm[e];
        float2 g = ((const float2*)(feat + (size_t)p.x * DIM))[lane];
        float v = __int_as_float(p.y);
        ax = fmaf(v, g.x, ax);  ay = fmaf(v, g.y, ay);
    }
    ((float2*)(aggr + (size_t)w * DIM))[lane] = make_float2(ax, ay);
}

// ---------------------------------------------------------------------------
// Fused  out = LN(ReLU(aggr @ W^T + b)) * scale + offset.  One wave per node.
// ---------------------------------------------------------------------------
__global__ __launch_bounds__(256) void gemm_relu_ln(
    const float* __restrict__ aggr, const float* __restrict__ W,
    const float* __restrict__ bias, const float* __restrict__ scale,
    const float* __restrict__ offset, float* __restrict__ out)
{
    __shared__ float sWt[DIM * 129];  // sWt[i*129 + o] = W[o][i]

    for (int idx = threadIdx.x; idx < DIM * DIM; idx += 256) {
        int o = idx >> 7;
        int i = idx & 127;
        sWt[i * 129 + o] = W[idx];
    }
    __syncthreads();

    const int lane = threadIdx.x & 63;
    const int wid  = threadIdx.x >> 6;

    const float b0 = bias[lane],    b1 = bias[lane + 64];
    const float s0 = scale[lane],   s1 = scale[lane + 64];
    const float f0 = offset[lane],  f1 = offset[lane + 64];

    for (int n = blockIdx.x * 4 + wid; n < N_NODES; n += gridDim.x * 4) {
        int nu = __builtin_amdgcn_readfirstlane(n);
        const float* arow = aggr + (size_t)nu * DIM;

        float acc0 = b0, acc1 = b1;
        #pragma unroll 8
        for (int i = 0; i < DIM; ++i) {
            float a = arow[i];
            acc0 = fmaf(a, sWt[i * 129 + lane], acc0);
            acc1 = fmaf(a, sWt[i * 129 + lane + 64], acc1);
        }

        float a0 = fmaxf(acc0, 0.0f);
        float a1 = fmaxf(acc1, 0.0f);

        float s = a0 + a1;
        #pragma unroll
        for (int off = 32; off >= 1; off >>= 1) s += __shfl_xor(s, off, 64);
        float mean = s * (1.0f / 128.0f);

        float d0 = a0 - mean, d1 = a1 - mean;
        float q = d0 * d0 + d1 * d1;
        #pragma unroll
        for (int off = 32; off >= 1; off >>= 1) q += __shfl_xor(q, off, 64);
        float rstd = rsqrtf(q * (1.0f / 128.0f) + LN_EPS);

        out[(size_t)n * DIM + lane]      = d0 * s0 * rstd + f0;
        out[(size_t)n * DIM + lane + 64] = d1 * s1 * rstd + f1;
    }
}

extern "C" void kernel_launch(void* const* d_in, const int* in_sizes, int n_in,
                              void* d_out, int out_size, void* d_ws, size_t ws_size,
                              hipStream_t stream) {
    const float* feat_in = (const float*)d_in[0];
    const int*   rows    = (const int*)d_in[1];
    const int*   cols    = (const int*)d_in[2];
    const float* vals    = (const float*)d_in[3];
    const float* W       = (const float*)d_in[4];
    const float* bias    = (const float*)d_in[5];
    const float* scale   = (const float*)d_in[6];
    const float* offset  = (const float*)d_in[7];
    float* out = (float*)d_out;

    // ---- workspace layout (all 256B-aligned) ----
    char* p = (char*)d_ws;
    float* aggr     = (float*)p;                 p += (size_t)N_NODES * DIM * 4;   // 25.6 MB
    int*   counts   = (int*)p;                   p += ((size_t)N_NODES + 64) * 4;
    int*   offsets  = (int*)p;                   p += ((size_t)N_NODES + 64) * 4;
    int*   cursor   = (int*)p;                   p += ((size_t)N_NODES + 64) * 4;
    int*   bsums    = (int*)p;                   p += 1024;
    int*   bpref    = (int*)p;                   p += 1024;
    int2*  perm     = (int2*)p;                  p += (size_t)N_EDGES * 8;         // 12.8 MB

    hipMemsetAsync(counts, 0, (size_t)N_NODES * sizeof(int), stream);

    int eb = (N_EDGES + 255) / 256;  // 6250
    hist_kernel   <<<eb, 256, 0, stream>>>(rows, counts);
    scan_blocksum <<<N_SCAN_BLOCKS, 256, 0, stream>>>(counts, bsums);
    scan_blockpref<<<1, 256, 0, stream>>>(bsums, bpref);
    scan_final    <<<N_SCAN_BLOCKS, 256, 0, stream>>>(counts, bpref, offsets, cursor);
    scatter_kernel<<<eb, 256, 0, stream>>>(rows, cols, vals, cursor, perm);

    int ab = (N_NODES * 64 + 255) / 256;  // 12500 blocks, one wave per row
    aggregate_kernel<<<ab, 256, 0, stream>>>(perm, offsets, feat_in, aggr);

    gemm_relu_ln<<<1024, 256, 0, stream>>>(aggr, W, bias, scale, offset, out);
}